// Round 13
// baseline (124.028 us; speedup 1.0000x reference)
//
#include <hip/hip_runtime.h>
#include <math.h>

#define TPB 256          // threads per block
#define QPT 2            // queries per thread -> 512-query span per block
#define QSPAN (TPB * QPT)
#define JWIN 256         // shared j-window per block, staged in LDS SoA (3 KB)
#define BIGV 1e10f
#define EPSV 1e-8f

// kernel 1: per 8-j tile and per query: 5-op exact chain -> diag patch (rare,
// wave-uniform) -> fmin tree (v_min3) -> 2-op (best, first-tile) update.
// Inner loop is software-pipelined: tile t+1's 6 ds_read_b128 are issued
// BEFORE tile t's compute (double-buffered named regs), hiding LDS latency
// behind ~50 independent VALU ops in-wave.
__global__ __launch_bounds__(TPB)
void esdf_nn(const float2* __restrict__ pc,
             unsigned long long* __restrict__ key, int n) {
#pragma clang fp contract(off)
    const int tid    = threadIdx.x;
    const int jparts = n / JWIN;                  // 64
    const int qblk   = blockIdx.x / jparts;       // 32 query blocks
    const int jpart  = blockIdx.x % jparts;
    const int qbase  = qblk * QSPAN;
    const int jbase  = jpart * JWIN;
    const bool self0 = (jbase == qbase);
    const bool self1 = (jbase == qbase + TPB);

    // --- stage j-window into LDS SoA; sq_j computed inline (exact formula) ---
    __shared__ float sXl[JWIN];
    __shared__ float sYl[JWIN];
    __shared__ float sSql[JWIN];
    if (tid < JWIN / 2) {
        float4 p4 = ((const float4*)pc)[(jbase >> 1) + tid];  // points 2t,2t+1
        int t2 = tid * 2;
        sXl[t2]     = p4.x;
        sYl[t2]     = p4.y;
        float xx0 = p4.x * p4.x, yy0 = p4.y * p4.y;
        sSql[t2]    = xx0 + yy0;
        sXl[t2 + 1] = p4.z;
        sYl[t2 + 1] = p4.w;
        float xx1 = p4.z * p4.z, yy1 = p4.w * p4.w;
        sSql[t2 + 1] = xx1 + yy1;
    }

    const int iq0 = qbase + tid;
    const int iq1 = qbase + TPB + tid;
    float2 p0 = pc[iq0], p1 = pc[iq1];
    const float x0 = p0.x, y0 = p0.y;
    const float s0 = (x0 * x0) + (y0 * y0);       // same bits as reference sq
    const float x1 = p1.x, y1 = p1.y;
    const float s1 = (x1 * x1) + (y1 * y1);
    __syncthreads();

    float best0 = BIGV, best1 = BIGV;
    int   bt0 = 0, bt1 = 0;
    const int w0 = iq0 >> 6, w1 = iq1 >> 6;       // wave-uniform query rows

    // double-buffered tile registers (named; no dynamic indexing)
    float4 xA0, xB0, yA0, yB0, sA0, sB0;          // buffer 0
    float4 xA1, xB1, yA1, yB1, sA1, sB1;          // buffer 1

#define LOADT(S, OFF)                                   \
    do {                                                \
        xA##S = *(const float4*)&sXl[(OFF)];            \
        xB##S = *(const float4*)&sXl[(OFF) + 4];        \
        yA##S = *(const float4*)&sYl[(OFF)];            \
        yB##S = *(const float4*)&sYl[(OFF) + 4];        \
        sA##S = *(const float4*)&sSql[(OFF)];           \
        sB##S = *(const float4*)&sSql[(OFF) + 4];       \
    } while (0)

    // process one 8-j tile (both queries) from buffer S at j-offset JT
#define PROC(S, JT)                                                          \
    do {                                                                     \
        const int j0_ = jbase + (JT);                                        \
        float xs[8] = {xA##S.x, xA##S.y, xA##S.z, xA##S.w,                   \
                       xB##S.x, xB##S.y, xB##S.z, xB##S.w};                  \
        float ys[8] = {yA##S.x, yA##S.y, yA##S.z, yA##S.w,                   \
                       yB##S.x, yB##S.y, yB##S.z, yB##S.w};                  \
        float ss[8] = {sA##S.x, sA##S.y, sA##S.z, sA##S.w,                   \
                       sB##S.x, sB##S.y, sB##S.z, sB##S.w};                  \
        const int tileId_ = j0_ >> 3;                                        \
        {                                                                    \
            float d[8];                                                      \
            _Pragma("unroll")                                                \
            for (int k = 0; k < 8; ++k) {                                    \
                float dot = fmaf(ys[k], y0, xs[k] * x0);                     \
                float s   = s0 + ss[k];                                      \
                float v   = fmaf(-2.0f, dot, s);                             \
                d[k] = fmaxf(v, 0.0f);                                       \
            }                                                                \
            if (self0 && ((j0_ >> 6) == w0)) {                               \
                _Pragma("unroll")                                            \
                for (int k = 0; k < 8; ++k)                                  \
                    if (j0_ + k == iq0) d[k] = BIGV;                         \
            }                                                                \
            float m01 = fminf(fminf(d[0], d[1]), d[2]);                      \
            float m23 = fminf(fminf(d[3], d[4]), d[5]);                      \
            float m45 = fminf(d[6], d[7]);                                   \
            float tmin = fminf(fminf(m01, m23), m45);                        \
            bool lt = tmin < best0;                                          \
            best0 = fminf(best0, tmin);                                      \
            bt0   = lt ? tileId_ : bt0;                                      \
        }                                                                    \
        {                                                                    \
            float d[8];                                                      \
            _Pragma("unroll")                                                \
            for (int k = 0; k < 8; ++k) {                                    \
                float dot = fmaf(ys[k], y1, xs[k] * x1);                     \
                float s   = s1 + ss[k];                                      \
                float v   = fmaf(-2.0f, dot, s);                             \
                d[k] = fmaxf(v, 0.0f);                                       \
            }                                                                \
            if (self1 && ((j0_ >> 6) == w1)) {                               \
                _Pragma("unroll")                                            \
                for (int k = 0; k < 8; ++k)                                  \
                    if (j0_ + k == iq1) d[k] = BIGV;                         \
            }                                                                \
            float m01 = fminf(fminf(d[0], d[1]), d[2]);                      \
            float m23 = fminf(fminf(d[3], d[4]), d[5]);                      \
            float m45 = fminf(d[6], d[7]);                                   \
            float tmin = fminf(fminf(m01, m23), m45);                        \
            bool lt = tmin < best1;                                          \
            best1 = fminf(best1, tmin);                                      \
            bt1   = lt ? tileId_ : bt1;                                      \
        }                                                                    \
    } while (0)

    LOADT(0, 0);                                  // prime the pipeline
#pragma unroll
    for (int jt = 0; jt < JWIN; jt += 16) {
        LOADT(1, jt + 8);                         // issue next tile's loads
        PROC(0, jt);                              // compute current tile
        if (jt + 16 < JWIN) LOADT(0, jt + 16);    // issue tile after next
        PROC(1, jt + 8);
    }
#undef LOADT
#undef PROC

    // key = (best_bits<<32)|tile; best>=0 so float order == unsigned order.
    unsigned long long k0 =
        ((unsigned long long)__float_as_uint(best0) << 32) | (unsigned)bt0;
    unsigned long long k1 =
        ((unsigned long long)__float_as_uint(best1) << 32) | (unsigned)bt1;
    // stale-skip: key[] only decreases, so skipping when kk >= read is safe
    unsigned long long c0 = *(const volatile unsigned long long*)&key[iq0];
    if (k0 < c0) atomicMin(&key[iq0], k0);
    unsigned long long c1 = *(const volatile unsigned long long*)&key[iq1];
    if (k1 < c1) atomicMin(&key[iq1], k1);
}

// kernel 2: recover exact argmin from the winning tile + epilogue
__global__ void esdf_finalize(const float2* __restrict__ pc,
                              const unsigned long long* __restrict__ key,
                              float* __restrict__ out, int n) {
#pragma clang fp contract(off)
    int q = blockIdx.x * blockDim.x + threadIdx.x;
    if (q >= n) return;
    unsigned long long k = key[q];
    float best = __uint_as_float((unsigned)(k >> 32));
    int   j0   = ((int)(k & 0xffffffffull)) << 3;

    float2 pq = pc[q];
    const float xq = pq.x, yq = pq.y;
    const float sqq = (xq * xq) + (yq * yq);      // same bits as reference sq

    int ix = j0;                                  // unreachable fallback
    bool found = false;
#pragma unroll
    for (int kk = 0; kk < 8; ++kk) {              // first j with d2 == best
        int j = j0 + kk;
        float2 pj = pc[j];
        float sj  = (pj.x * pj.x) + (pj.y * pj.y);
        float dot = fmaf(pj.y, yq, pj.x * xq);    // exact recompute, same bits
        float s   = sqq + sj;
        float v   = fmaf(-2.0f, dot, s);
        v = fmaxf(v, 0.0f);
        if (!found && j != q && v == best) { ix = j; found = true; }
    }

    float esdf = sqrtf(best);
    float2 pn = pc[ix];
    float dx = xq - pn.x;
    float dy = yq - pn.y;
    float a  = dx * dx;
    float c2 = dy * dy;
    float nrm = sqrtf(a + c2);
    float inv = nrm + EPSV;
    float gx = dx / inv;
    float gy = dy / inv;
    // out = mu(4,N) then lam(3,N), flat
    out[0 * n + q] = gx;
    out[1 * n + q] = -gx;
    out[2 * n + q] = gy;
    out[3 * n + q] = -gy;
    out[4 * n + q] = gx;
    out[5 * n + q] = gy;
    out[6 * n + q] = esdf / 10.0f;
}

extern "C" void kernel_launch(void* const* d_in, const int* in_sizes, int n_in,
                              void* d_out, int out_size, void* d_ws, size_t ws_size,
                              hipStream_t stream) {
    const float2* pc = (const float2*)d_in[0];
    float* out = (float*)d_out;
    const int n = in_sizes[0] / 2;               // 16384

    // ws layout: key[n] u64 (128KB); 0xFF-fill == ~0ull init
    unsigned long long* key = (unsigned long long*)d_ws;
    hipMemsetAsync(key, 0xFF, n * sizeof(unsigned long long), stream);

    const int jparts = n / JWIN;                 // 64
    const int qblks  = n / QSPAN;                // 32

    esdf_nn<<<qblks * jparts, TPB, 0, stream>>>(pc, key, n);
    esdf_finalize<<<(n + 255) / 256, 256, 0, stream>>>(pc, key, out, n);
}

// Round 14
// 48.124 us; speedup vs baseline: 2.5772x; 2.5772x over previous
//
#include <hip/hip_runtime.h>
#include <math.h>

#define TPB 256          // threads per block
#define QPT 2            // queries per thread -> 512-query span per block
#define QSPAN (TPB * QPT)
#define JWIN 256         // shared j-window per block, staged in LDS SoA (3 KB)
#define BIGV 1e10f
#define EPSV 1e-8f

// kernel 1: per 8-j tile and per query: 5-op exact chain -> diag patch (rare,
// wave-uniform) -> fmin tree (v_min3) -> 2-op (best, first-tile) update.
// sq recomputed inline (bit-identical to reference sum(pc*pc,axis=1)).
// Cross-block merge: atomicMin on key=(best_bits<<32)|tile; lexicographic ==
// numpy first-index argmin (earliest tile, then finalize picks lowest j).
__global__ __launch_bounds__(TPB)
void esdf_nn(const float2* __restrict__ pc,
             unsigned long long* __restrict__ key, int n) {
#pragma clang fp contract(off)
    const int tid    = threadIdx.x;
    const int jparts = n / JWIN;                  // 64
    const int qblk   = blockIdx.x / jparts;       // 32 query blocks
    const int jpart  = blockIdx.x % jparts;
    const int qbase  = qblk * QSPAN;
    const int jbase  = jpart * JWIN;
    // self-point of query group m lies in this window iff jbase == qbase+m*256
    const bool self0 = (jbase == qbase);
    const bool self1 = (jbase == qbase + TPB);

    // --- stage j-window into LDS SoA; sq_j computed inline (exact formula) ---
    __shared__ float sXl[JWIN];
    __shared__ float sYl[JWIN];
    __shared__ float sSql[JWIN];
    if (tid < JWIN / 2) {
        float4 p4 = ((const float4*)pc)[(jbase >> 1) + tid];  // points 2t,2t+1
        int t2 = tid * 2;
        sXl[t2]     = p4.x;
        sYl[t2]     = p4.y;
        float xx0 = p4.x * p4.x, yy0 = p4.y * p4.y;
        sSql[t2]    = xx0 + yy0;
        sXl[t2 + 1] = p4.z;
        sYl[t2 + 1] = p4.w;
        float xx1 = p4.z * p4.z, yy1 = p4.w * p4.w;
        sSql[t2 + 1] = xx1 + yy1;
    }

    // per-thread query registers (2 queries; sq recomputed, same bits)
    const int iq0 = qbase + tid;
    const int iq1 = qbase + TPB + tid;
    float2 p0 = pc[iq0], p1 = pc[iq1];
    const float x0 = p0.x, y0 = p0.y;
    const float s0 = (x0 * x0) + (y0 * y0);
    const float x1 = p1.x, y1 = p1.y;
    const float s1 = (x1 * x1) + (y1 * y1);
    __syncthreads();

    float best0 = BIGV, best1 = BIGV;
    int   bt0 = 0, bt1 = 0;
    const int w0 = iq0 >> 6, w1 = iq1 >> 6;       // wave-uniform query rows

    for (int jt = 0; jt < JWIN; jt += 8) {
        const int j0 = jbase + jt;                // block-uniform
        float4 xA = *(const float4*)&sXl[jt];     // 6x ds_read_b128
        float4 xB = *(const float4*)&sXl[jt + 4];
        float4 yA = *(const float4*)&sYl[jt];
        float4 yB = *(const float4*)&sYl[jt + 4];
        float4 sA = *(const float4*)&sSql[jt];
        float4 sB = *(const float4*)&sSql[jt + 4];
        float xs[8] = {xA.x, xA.y, xA.z, xA.w, xB.x, xB.y, xB.z, xB.w};
        float ys[8] = {yA.x, yA.y, yA.z, yA.w, yB.x, yB.y, yB.z, yB.w};
        float ss[8] = {sA.x, sA.y, sA.z, sA.w, sB.x, sB.y, sB.z, sB.w};
        const int tileId = j0 >> 3;               // uniform (SGPR)

        // ---- query 0 ----
        {
            float d[8];
#pragma unroll
            for (int k = 0; k < 8; ++k) {         // exact reference rounding
                float dot = fmaf(ys[k], y0, xs[k] * x0);   // BLAS fma order
                float s   = s0 + ss[k];
                float v   = fmaf(-2.0f, dot, s);
                d[k] = fmaxf(v, 0.0f);
            }
            if (self0 && ((j0 >> 6) == w0)) {     // rare, wave-uniform
#pragma unroll
                for (int k = 0; k < 8; ++k)
                    if (j0 + k == iq0) d[k] = BIGV;   // mirror reference +eye*BIG
            }
            float m01 = fminf(fminf(d[0], d[1]), d[2]);
            float m23 = fminf(fminf(d[3], d[4]), d[5]);
            float m45 = fminf(d[6], d[7]);
            float tmin = fminf(fminf(m01, m23), m45);
            bool lt = tmin < best0;               // strict < keeps earliest tile
            best0 = fminf(best0, tmin);
            bt0   = lt ? tileId : bt0;
        }
        // ---- query 1 ----
        {
            float d[8];
#pragma unroll
            for (int k = 0; k < 8; ++k) {
                float dot = fmaf(ys[k], y1, xs[k] * x1);
                float s   = s1 + ss[k];
                float v   = fmaf(-2.0f, dot, s);
                d[k] = fmaxf(v, 0.0f);
            }
            if (self1 && ((j0 >> 6) == w1)) {
#pragma unroll
                for (int k = 0; k < 8; ++k)
                    if (j0 + k == iq1) d[k] = BIGV;
            }
            float m01 = fminf(fminf(d[0], d[1]), d[2]);
            float m23 = fminf(fminf(d[3], d[4]), d[5]);
            float m45 = fminf(d[6], d[7]);
            float tmin = fminf(fminf(m01, m23), m45);
            bool lt = tmin < best1;
            best1 = fminf(best1, tmin);
            bt1   = lt ? tileId : bt1;
        }
    }

    // key = (best_bits<<32)|tile; best>=0 so float order == unsigned order.
    unsigned long long k0 =
        ((unsigned long long)__float_as_uint(best0) << 32) | (unsigned)bt0;
    unsigned long long k1 =
        ((unsigned long long)__float_as_uint(best1) << 32) | (unsigned)bt1;
    // stale-skip: key[] only decreases, so skipping when kk >= read is safe
    unsigned long long c0 = *(const volatile unsigned long long*)&key[iq0];
    if (k0 < c0) atomicMin(&key[iq0], k0);
    unsigned long long c1 = *(const volatile unsigned long long*)&key[iq1];
    if (k1 < c1) atomicMin(&key[iq1], k1);
}

// kernel 2: recover exact argmin from the winning tile + epilogue
__global__ void esdf_finalize(const float2* __restrict__ pc,
                              const unsigned long long* __restrict__ key,
                              float* __restrict__ out, int n) {
#pragma clang fp contract(off)
    int q = blockIdx.x * blockDim.x + threadIdx.x;
    if (q >= n) return;
    unsigned long long k = key[q];
    float best = __uint_as_float((unsigned)(k >> 32));
    int   j0   = ((int)(k & 0xffffffffull)) << 3;

    float2 pq = pc[q];
    const float xq = pq.x, yq = pq.y;
    const float sqq = (xq * xq) + (yq * yq);      // same bits as reference sq

    int ix = j0;                                  // unreachable fallback
    bool found = false;
#pragma unroll
    for (int kk = 0; kk < 8; ++kk) {              // first j with d2 == best
        int j = j0 + kk;
        float2 pj = pc[j];
        float sj  = (pj.x * pj.x) + (pj.y * pj.y);
        float dot = fmaf(pj.y, yq, pj.x * xq);    // exact recompute, same bits
        float s   = sqq + sj;
        float v   = fmaf(-2.0f, dot, s);
        v = fmaxf(v, 0.0f);
        if (!found && j != q && v == best) { ix = j; found = true; }
    }

    float esdf = sqrtf(best);
    float2 pn = pc[ix];
    float dx = xq - pn.x;
    float dy = yq - pn.y;
    float a  = dx * dx;
    float c2 = dy * dy;
    float nrm = sqrtf(a + c2);
    float inv = nrm + EPSV;
    float gx = dx / inv;
    float gy = dy / inv;
    // out = mu(4,N) then lam(3,N), flat
    out[0 * n + q] = gx;
    out[1 * n + q] = -gx;
    out[2 * n + q] = gy;
    out[3 * n + q] = -gy;
    out[4 * n + q] = gx;
    out[5 * n + q] = gy;
    out[6 * n + q] = esdf / 10.0f;
}

extern "C" void kernel_launch(void* const* d_in, const int* in_sizes, int n_in,
                              void* d_out, int out_size, void* d_ws, size_t ws_size,
                              hipStream_t stream) {
    const float2* pc = (const float2*)d_in[0];
    float* out = (float*)d_out;
    const int n = in_sizes[0] / 2;               // 16384

    // ws layout: key[n] u64 (128KB); 0xFF-fill == ~0ull init
    unsigned long long* key = (unsigned long long*)d_ws;
    hipMemsetAsync(key, 0xFF, n * sizeof(unsigned long long), stream);

    const int jparts = n / JWIN;                 // 64
    const int qblks  = n / QSPAN;                // 32

    esdf_nn<<<qblks * jparts, TPB, 0, stream>>>(pc, key, n);
    esdf_finalize<<<(n + 255) / 256, 256, 0, stream>>>(pc, key, out, n);
}